// Round 1
// baseline (3062.878 us; speedup 1.0000x reference)
//
#include <hip/hip_runtime.h>

#define SEQLEN 2048
#define NHEADS 8
#define HD 64
#define EMB 512
#define NB 2

// ---------------- Kernel 1: per-head QKV projections ----------------
// out[n,h,s,d] = b[d] + sum_j W[d,j] * x[n,s,h*64+j]
__global__ __launch_bounds__(256) void proj_kernel(
    const float* __restrict__ q, const float* __restrict__ k, const float* __restrict__ v,
    const float* __restrict__ Wq, const float* __restrict__ bq,
    const float* __restrict__ Wk, const float* __restrict__ bk,
    const float* __restrict__ Wv, const float* __restrict__ bv,
    float* __restrict__ Qh, float* __restrict__ Kh, float* __restrict__ Vh)
{
    const float* x; const float* W; const float* b; float* dst;
    switch (blockIdx.y) {
      case 0:  x = q; W = Wq; b = bq; dst = Qh; break;
      case 1:  x = k; W = Wk; b = bk; dst = Kh; break;
      default: x = v; W = Wv; b = bv; dst = Vh; break;
    }
    __shared__ float Ws[64 * 65];   // padded: bank-conflict-free row reads
    __shared__ float Bs[64];
    const int tid = threadIdx.x;
    for (int idx = tid; idx < 64 * 64; idx += 256)
        Ws[(idx >> 6) * 65 + (idx & 63)] = W[idx];
    if (tid < 64) Bs[tid] = b[tid];
    __syncthreads();

    const int r = blockIdx.x * 4 + (tid >> 6);      // global (n,s,h) row
    const int d = tid & 63;
    const int n   = r / (SEQLEN * NHEADS);
    const int rem = r - n * (SEQLEN * NHEADS);
    const int s   = rem / NHEADS;
    const int h   = rem - s * NHEADS;

    const float* xr = x + ((size_t)(n * SEQLEN + s)) * EMB + h * HD;
    const float* wr = Ws + d * 65;
    float acc = Bs[d];
    #pragma unroll 16
    for (int j = 0; j < 64; ++j)
        acc += wr[j] * xr[j];
    Qh = nullptr; // (unused; silence nothing) -- no-op
    dst[(((size_t)(n * NHEADS + h)) * SEQLEN + s) * HD + d] = acc;
}

// ---------------- Kernel 2: attention row ----------------
// block = (n, h, q). P = softmax over strictly-upper scores (faithful -1e20 mask),
// then w[c] = P[c] + (c<=q ? Q·E[S-1-q+c] : 0), then z = w @ V.
__global__ __launch_bounds__(256) void attn_kernel(
    const float* __restrict__ Qh, const float* __restrict__ Kh,
    const float* __restrict__ Vh, const float* __restrict__ E,
    float* __restrict__ Z)
{
    const int qi  = blockIdx.x;
    const int h   = blockIdx.y;
    const int n   = blockIdx.z;
    const int tid = threadIdx.x;

    __shared__ float Qs[HD];
    __shared__ float sc[SEQLEN];
    __shared__ float red[4];
    __shared__ float ps[4][HD];

    const size_t hb = ((size_t)(n * NHEADS + h)) * SEQLEN * HD;
    if (tid < HD) Qs[tid] = Qh[hb + (size_t)qi * HD + tid];
    __syncthreads();

    const float scale = 0.04419417382415922f;        // 1/sqrt(512)
    const float NEG   = -1e20f * scale;              // faithful masked value

    // ---- scores + local max ----
    float lmax = -3.4e38f;
    for (int kk = tid; kk < SEQLEN; kk += 256) {
        float val;
        if (kk > qi) {
            const float* kr = Kh + hb + (size_t)kk * HD;
            float acc = 0.f;
            #pragma unroll
            for (int j = 0; j < HD; j += 4) {
                float4 kv = *reinterpret_cast<const float4*>(kr + j);
                acc += kv.x * Qs[j] + kv.y * Qs[j + 1] + kv.z * Qs[j + 2] + kv.w * Qs[j + 3];
            }
            val = acc * scale;
        } else {
            val = NEG;
        }
        sc[kk] = val;
        lmax = fmaxf(lmax, val);
    }
    #pragma unroll
    for (int o = 32; o > 0; o >>= 1) lmax = fmaxf(lmax, __shfl_xor(lmax, o, 64));
    if ((tid & 63) == 0) red[tid >> 6] = lmax;
    __syncthreads();
    const float m = fmaxf(fmaxf(red[0], red[1]), fmaxf(red[2], red[3]));
    __syncthreads();   // red reused below

    // ---- exp + sum ----
    float lsum = 0.f;
    for (int kk = tid; kk < SEQLEN; kk += 256) {
        float e = expf(sc[kk] - m);   // masked: exp(-4.4e18 - m) -> 0; uniform row: exp(0)=1
        sc[kk] = e;
        lsum += e;
    }
    #pragma unroll
    for (int o = 32; o > 0; o >>= 1) lsum += __shfl_xor(lsum, o, 64);
    if ((tid & 63) == 0) red[tid >> 6] = lsum;
    __syncthreads();
    const float inv = 1.f / (red[0] + red[1] + red[2] + red[3]);

    // ---- normalize + add Srel (same per-index ownership as above: no race) ----
    for (int c = tid; c < SEQLEN; c += 256) {
        float w = sc[c] * inv;
        if (c <= qi) {
            const float* er = E + (size_t)(SEQLEN - 1 - qi + c) * HD;
            float acc = 0.f;
            #pragma unroll
            for (int j = 0; j < HD; j += 4) {
                float4 ev = *reinterpret_cast<const float4*>(er + j);
                acc += ev.x * Qs[j] + ev.y * Qs[j + 1] + ev.z * Qs[j + 2] + ev.w * Qs[j + 3];
            }
            w += acc;
        }
        sc[c] = w;
    }
    __syncthreads();

    // ---- (P + Srel) @ V ----
    const int d  = tid & 63;
    const int ch = tid >> 6;
    const float* vb = Vh + hb + d;
    float acc = 0.f;
    const int k0 = ch * (SEQLEN / 4);
    for (int kk = k0; kk < k0 + SEQLEN / 4; ++kk)
        acc += sc[kk] * vb[(size_t)kk * HD];
    ps[ch][d] = acc;
    __syncthreads();
    if (tid < HD) {
        float z = ps[0][tid] + ps[1][tid] + ps[2][tid] + ps[3][tid];
        Z[(((size_t)(n * SEQLEN + qi)) * NHEADS + h) * HD + tid] = z;
    }
}

// ---------------- Kernel 3: output projection ----------------
__global__ __launch_bounds__(256) void oproj_kernel(
    const float* __restrict__ Z, const float* __restrict__ Wo,
    const float* __restrict__ bo, float* __restrict__ out)
{
    const int t   = blockIdx.x;           // token index in [0, N*S)
    const int tid = threadIdx.x;
    __shared__ float zs[EMB];
    zs[tid]       = Z[(size_t)t * EMB + tid];
    zs[tid + 256] = Z[(size_t)t * EMB + tid + 256];
    __syncthreads();

    #pragma unroll
    for (int oo = 0; oo < 2; ++oo) {
        const int o = tid + oo * 256;
        const float4* wr = reinterpret_cast<const float4*>(Wo + (size_t)o * EMB);
        float acc = bo[o];
        #pragma unroll 8
        for (int i = 0; i < EMB / 4; ++i) {
            float4 w4 = wr[i];
            acc += w4.x * zs[4 * i] + w4.y * zs[4 * i + 1] + w4.z * zs[4 * i + 2] + w4.w * zs[4 * i + 3];
        }
        out[(size_t)t * EMB + o] = acc;
    }
}

extern "C" void kernel_launch(void* const* d_in, const int* in_sizes, int n_in,
                              void* d_out, int out_size, void* d_ws, size_t ws_size,
                              hipStream_t stream) {
    const float* v  = (const float*)d_in[0];
    const float* k  = (const float*)d_in[1];
    const float* q  = (const float*)d_in[2];
    const float* Wv = (const float*)d_in[3];
    const float* bv = (const float*)d_in[4];
    const float* Wk = (const float*)d_in[5];
    const float* bk = (const float*)d_in[6];
    const float* Wq = (const float*)d_in[7];
    const float* bq = (const float*)d_in[8];
    const float* E  = (const float*)d_in[9];
    const float* Wo = (const float*)d_in[10];
    const float* bo = (const float*)d_in[11];
    float* out = (float*)d_out;

    // workspace: Qh, Kh, Vh [N,H,S,64] + Z [N,S,512]  => 32 MB total
    float* ws = (float*)d_ws;
    const size_t per = (size_t)NB * NHEADS * SEQLEN * HD;   // 2,097,152 floats
    float* Qh = ws;
    float* Kh = ws + per;
    float* Vh = ws + 2 * per;
    float* Zb = ws + 3 * per;

    dim3 g1(NB * SEQLEN * NHEADS / 4, 3);
    proj_kernel<<<g1, 256, 0, stream>>>(q, k, v, Wq, bq, Wk, bk, Wv, bv, Qh, Kh, Vh);

    dim3 g2(SEQLEN, NHEADS, NB);
    attn_kernel<<<g2, 256, 0, stream>>>(Qh, Kh, Vh, E, Zb);

    oproj_kernel<<<NB * SEQLEN, 256, 0, stream>>>(Zb, Wo, bo, out);
}

// Round 3
// 670.907 us; speedup vs baseline: 4.5653x; 4.5653x over previous
//
#include <hip/hip_runtime.h>
#include <hip/hip_bf16.h>

#define SEQLEN 2048
#define NHEADS 8
#define HD 64
#define EMB 512
#define NB 2
#define ST 72   // padded LDS stride in bf16 units (144 B = 9 x 16B -> full bank spread)

typedef __attribute__((ext_vector_type(8))) short bf16x8;
typedef __attribute__((ext_vector_type(4))) float f32x4;

#define SCALE 0.04419417382415922f
#define NEGS  (-4.4194173824159216e18f)   // -1e20 * SCALE (faithful masked score)

__device__ __forceinline__ ushort f2b(float f) {
    __hip_bfloat16 h = __float2bfloat16(f);
    return *reinterpret_cast<ushort*>(&h);
}
__device__ __forceinline__ float b2f(ushort u) {
    unsigned int v = ((unsigned int)u) << 16;
    return __builtin_bit_cast(float, v);
}

// ---------------- Kernel 1: per-head QKV projections (bf16 out) ----------------
__global__ __launch_bounds__(256) void proj_kernel(
    const float* __restrict__ q, const float* __restrict__ k, const float* __restrict__ v,
    const float* __restrict__ Wq, const float* __restrict__ bq,
    const float* __restrict__ Wk, const float* __restrict__ bk,
    const float* __restrict__ Wv, const float* __restrict__ bv,
    ushort* __restrict__ Qh, ushort* __restrict__ Kh, ushort* __restrict__ Vh)
{
    const float* x; const float* W; const float* b; ushort* dst;
    switch (blockIdx.y) {
      case 0:  x = q; W = Wq; b = bq; dst = Qh; break;
      case 1:  x = k; W = Wk; b = bk; dst = Kh; break;
      default: x = v; W = Wv; b = bv; dst = Vh; break;
    }
    __shared__ float Ws[64 * 65];
    __shared__ float Bs[64];
    const int tid = threadIdx.x;
    for (int idx = tid; idx < 64 * 64; idx += 256)
        Ws[(idx >> 6) * 65 + (idx & 63)] = W[idx];
    if (tid < 64) Bs[tid] = b[tid];
    __syncthreads();

    const int r = blockIdx.x * 4 + (tid >> 6);
    const int d = tid & 63;
    const int n   = r / (SEQLEN * NHEADS);
    const int rem = r - n * (SEQLEN * NHEADS);
    const int s   = rem / NHEADS;
    const int h   = rem - s * NHEADS;

    const float* xr = x + ((size_t)(n * SEQLEN + s)) * EMB + h * HD;
    const float* wr = Ws + d * 65;
    float acc = Bs[d];
    #pragma unroll 16
    for (int j = 0; j < 64; ++j)
        acc += wr[j] * xr[j];
    dst[(((size_t)(n * NHEADS + h)) * SEQLEN + s) * HD + d] = f2b(acc);
}

// ---------------- Kernel 1b: V transpose  [n,h,s,d] -> [n,h,d,s] ----------------
__global__ __launch_bounds__(256) void vtrans_kernel(
    const ushort* __restrict__ Vh, ushort* __restrict__ VT)
{
    __shared__ alignas(16) ushort ts[64 * 72];
    const int tid = threadIdx.x;
    const int s0 = blockIdx.x * 64;
    const size_t hb = ((size_t)(blockIdx.z * NHEADS + blockIdx.y)) * SEQLEN * HD;
    const int r = tid >> 2;
    const int cc = (tid & 3) * 16;
    uint4 a = *(const uint4*)(Vh + hb + (size_t)(s0 + r) * HD + cc);
    uint4 b = *(const uint4*)(Vh + hb + (size_t)(s0 + r) * HD + cc + 8);
    *(uint4*)&ts[r * 72 + cc] = a;
    *(uint4*)&ts[r * 72 + cc + 8] = b;
    __syncthreads();
    const int d = tid >> 2;
    const int sc0 = (tid & 3) * 16;
    ushort tmp[16];
    #pragma unroll
    for (int i = 0; i < 16; ++i) tmp[i] = ts[(sc0 + i) * 72 + d];
    *(uint4*)(VT + hb + (size_t)d * SEQLEN + s0 + sc0)     = *(uint4*)&tmp[0];
    *(uint4*)(VT + hb + (size_t)d * SEQLEN + s0 + sc0 + 8) = *(uint4*)&tmp[8];
}

// ---------------- Kernel 1c: E f32 -> bf16 ----------------
__global__ __launch_bounds__(256) void econv_kernel(
    const float* __restrict__ E, ushort* __restrict__ Eb)
{
    const int i = (blockIdx.x * 256 + threadIdx.x) * 4;
    float4 f = *(const float4*)(E + i);
    ushort4 u;
    u.x = f2b(f.x); u.y = f2b(f.y); u.z = f2b(f.z); u.w = f2b(f.w);
    *(ushort4*)(Eb + i) = u;
}

// ---------------- Kernel 2: MFMA flash attention with skewed rel-pos ----------------
// grid (S/64, H, N), 256 threads = 4 waves; wave w owns rows qw..qw+15.
// z[q] = (1/l) * sum_{c} e[q,c] V[c]  +  sum_{c<=q} (Q[q]*E[S-1-q+c]) V[c]
__global__ __launch_bounds__(256, 2) void attn_mfma(
    const ushort* __restrict__ Qh, const ushort* __restrict__ Kh,
    const ushort* __restrict__ VT, const ushort* __restrict__ Eb,
    float* __restrict__ Z)
{
    const int q0 = blockIdx.x * 64;
    const int h = blockIdx.y, n = blockIdx.z;
    const int tid = threadIdx.x;
    const int w = tid >> 6;
    const int l = tid & 63;
    const int l15 = l & 15, l16 = l >> 4;

    __shared__ alignas(16) ushort Kt[64 * ST];
    __shared__ alignas(16) ushort Vt[64 * ST];      // transposed: Vt[d][c]
    __shared__ alignas(16) ushort Et[128 * ST];
    __shared__ alignas(16) ushort Wt[4][16 * ST];   // per-wave weight tile
    __shared__ float vpart[4][64];
    __shared__ float vsum[64];

    const size_t hb = ((size_t)(n * NHEADS + h)) * SEQLEN * HD;
    const bool lastBlk = (q0 == SEQLEN - 64);
    const int qw = q0 + 16 * w;

    // Q A-fragments (rows qw + l15, k-chunks)
    bf16x8 qa[2];
    {
        const ushort* qp = Qh + hb + (size_t)(qw + l15) * HD + l16 * 8;
        qa[0] = *(const bf16x8*)(qp);
        qa[1] = *(const bf16x8*)(qp + 32);
    }

    f32x4 zp[4], zr[4];
    #pragma unroll
    for (int nb = 0; nb < 4; ++nb) {
        zp[nb] = (f32x4){0.f, 0.f, 0.f, 0.f};
        zr[nb] = (f32x4){0.f, 0.f, 0.f, 0.f};
    }
    float mrow[4], lrow[4];
    #pragma unroll
    for (int r = 0; r < 4; ++r) { mrow[r] = NEGS; lrow[r] = 0.f; }
    float vloc = 0.f;

    for (int t = 0; t < 32; ++t) {
        const int c0 = t * 64;
        const bool hasP = (c0 >= q0);
        const bool hasR = (c0 <= q0);
        const bool diag = (c0 == q0);

        __syncthreads();   // prev tile's PV done before restaging
        {
            const int r8 = tid >> 3;
            const int ch8 = (tid & 7) * 8;
            uint4 v0 = *(const uint4*)(VT + hb + (size_t)r8 * SEQLEN + c0 + ch8);
            uint4 v1 = *(const uint4*)(VT + hb + (size_t)(r8 + 32) * SEQLEN + c0 + ch8);
            uint4 k0, k1;
            if (hasP) {
                k0 = *(const uint4*)(Kh + hb + (size_t)(c0 + r8) * HD + ch8);
                k1 = *(const uint4*)(Kh + hb + (size_t)(c0 + r8 + 32) * HD + ch8);
            }
            uint4 e[4];
            int jmin = 0;
            if (hasR) {
                jmin = SEQLEN - 64 - q0 + c0;
                #pragma unroll
                for (int i = 0; i < 4; ++i) {
                    const int j = jmin + r8 + 32 * i;
                    if (j < SEQLEN) e[i] = *(const uint4*)(Eb + (size_t)j * HD + ch8);
                    else e[i] = make_uint4(0u, 0u, 0u, 0u);
                }
            }
            *(uint4*)&Vt[r8 * ST + ch8] = v0;
            *(uint4*)&Vt[(r8 + 32) * ST + ch8] = v1;
            if (hasP) {
                *(uint4*)&Kt[r8 * ST + ch8] = k0;
                *(uint4*)&Kt[(r8 + 32) * ST + ch8] = k1;
            }
            if (hasR) {
                #pragma unroll
                for (int i = 0; i < 4; ++i)
                    *(uint4*)&Et[(r8 + 32 * i) * ST + ch8] = e[i];
            }
        }
        __syncthreads();

        if (lastBlk) {   // accumulate column-sum of V (for uniform row S-1)
            const uint4 a = *(const uint4*)&Vt[l * ST + 16 * w];
            const uint4 b = *(const uint4*)&Vt[l * ST + 16 * w + 8];
            const ushort* pa = (const ushort*)&a;
            const ushort* pb = (const ushort*)&b;
            #pragma unroll
            for (int i = 0; i < 8; ++i) vloc += b2f(pa[i]) + b2f(pb[i]);
        }

        // ---------- P (softmax) part ----------
        if (hasP) {
            f32x4 sc[4];
            #pragma unroll
            for (int nb = 0; nb < 4; ++nb) sc[nb] = (f32x4){0.f, 0.f, 0.f, 0.f};
            #pragma unroll
            for (int ks = 0; ks < 2; ++ks) {
                const int ko = ks * 32 + l16 * 8;
                #pragma unroll
                for (int nb = 0; nb < 4; ++nb) {
                    bf16x8 kb = *(const bf16x8*)&Kt[(nb * 16 + l15) * ST + ko];
                    sc[nb] = __builtin_amdgcn_mfma_f32_16x16x32_bf16(qa[ks], kb, sc[nb], 0, 0, 0);
                }
            }
            float sv[4][4], mt[4], frs[4];
            #pragma unroll
            for (int r = 0; r < 4; ++r) mt[r] = NEGS;
            #pragma unroll
            for (int nb = 0; nb < 4; ++nb)
                #pragma unroll
                for (int r = 0; r < 4; ++r) {
                    float s = sc[nb][r] * SCALE;
                    if (diag && (nb * 16 + l15 <= 16 * w + l16 * 4 + r)) s = NEGS;
                    sv[nb][r] = s;
                    mt[r] = fmaxf(mt[r], s);
                }
            #pragma unroll
            for (int r = 0; r < 4; ++r) {
                #pragma unroll
                for (int off = 1; off < 16; off <<= 1)
                    mt[r] = fmaxf(mt[r], __shfl_xor(mt[r], off, 64));
                const float mn = fmaxf(mrow[r], mt[r]);
                frs[r] = __expf(mrow[r] - mn);
                mrow[r] = mn;
                lrow[r] *= frs[r];
            }
            float se[4] = {0.f, 0.f, 0.f, 0.f};
            #pragma unroll
            for (int nb = 0; nb < 4; ++nb)
                #pragma unroll
                for (int r = 0; r < 4; ++r) {
                    const float e = __expf(sv[nb][r] - mrow[r]);
                    se[r] += e;
                    Wt[w][(l16 * 4 + r) * ST + nb * 16 + l15] = f2b(e);
                }
            #pragma unroll
            for (int r = 0; r < 4; ++r) {
                #pragma unroll
                for (int off = 1; off < 16; off <<= 1)
                    se[r] += __shfl_xor(se[r], off, 64);
                lrow[r] += se[r];
            }
            #pragma unroll
            for (int nb = 0; nb < 4; ++nb)
                #pragma unroll
                for (int r = 0; r < 4; ++r) zp[nb][r] *= frs[r];
            // PV into zp (reads own wave's Wt; in-wave ds ordering by compiler)
            #pragma unroll
            for (int ks = 0; ks < 2; ++ks) {
                const int ko = ks * 32 + l16 * 8;
                bf16x8 wa = *(const bf16x8*)&Wt[w][l15 * ST + ko];
                #pragma unroll
                for (int nb = 0; nb < 4; ++nb) {
                    bf16x8 vb = *(const bf16x8*)&Vt[(nb * 16 + l15) * ST + ko];
                    zp[nb] = __builtin_amdgcn_mfma_f32_16x16x32_bf16(wa, vb, zp[nb], 0, 0, 0);
                }
            }
        }

        // ---------- rel (Srel) part ----------
        if (hasR) {
            const int jbase = 48 - 16 * w;   // wave's window into Et
            f32x4 qe[5];
            #pragma unroll
            for (int jb = 0; jb < 5; ++jb) qe[jb] = (f32x4){0.f, 0.f, 0.f, 0.f};
            #pragma unroll
            for (int ks = 0; ks < 2; ++ks) {
                const int ko = ks * 32 + l16 * 8;
                #pragma unroll
                for (int jb = 0; jb < 5; ++jb) {
                    bf16x8 eb = *(const bf16x8*)&Et[(jbase + jb * 16 + l15) * ST + ko];
                    qe[jb] = __builtin_amdgcn_mfma_f32_16x16x32_bf16(qa[ks], eb, qe[jb], 0, 0, 0);
                }
            }
            // scatter skewed: (q, j) -> (q, cloc = jl + rowloc - 15); write srel if c<=q else 0
            #pragma unroll
            for (int jb = 0; jb < 5; ++jb)
                #pragma unroll
                for (int r = 0; r < 4; ++r) {
                    const int rowloc = l16 * 4 + r;
                    const int cloc = jb * 16 + l15 + rowloc - 15;
                    if (cloc >= 0 && cloc < 64) {
                        const bool msk = (c0 + cloc <= qw + rowloc);
                        Wt[w][rowloc * ST + cloc] = f2b(msk ? qe[jb][r] : 0.f);
                    }
                }
            // PV into zr
            #pragma unroll
            for (int ks = 0; ks < 2; ++ks) {
                const int ko = ks * 32 + l16 * 8;
                bf16x8 wa = *(const bf16x8*)&Wt[w][l15 * ST + ko];
                #pragma unroll
                for (int nb = 0; nb < 4; ++nb) {
                    bf16x8 vb = *(const bf16x8*)&Vt[(nb * 16 + l15) * ST + ko];
                    zr[nb] = __builtin_amdgcn_mfma_f32_16x16x32_bf16(wa, vb, zr[nb], 0, 0, 0);
                }
            }
        }
    }

    // ---------- vsum finalize (uniform row S-1) ----------
    if (lastBlk) vpart[w][l] = vloc;
    __syncthreads();
    if (lastBlk && tid < 64)
        vsum[tid] = vpart[0][tid] + vpart[1][tid] + vpart[2][tid] + vpart[3][tid];
    __syncthreads();

    // ---------- epilogue ----------
    float invl[4];
    #pragma unroll
    for (int r = 0; r < 4; ++r) invl[r] = 1.f / lrow[r];
    #pragma unroll
    for (int nb = 0; nb < 4; ++nb)
        #pragma unroll
        for (int r = 0; r < 4; ++r) {
            const int q = qw + l16 * 4 + r;
            const int d = nb * 16 + l15;
            float z = zp[nb][r] * invl[r] + zr[nb][r];
            if (lastBlk && q == SEQLEN - 1)
                z = vsum[d] * (1.f / (float)SEQLEN) + zr[nb][r];
            Z[((size_t)(n * SEQLEN + q)) * EMB + h * HD + d] = z;
        }
}

// ---------------- Kernel 3: output projection ----------------
__global__ __launch_bounds__(256) void oproj_kernel(
    const float* __restrict__ Z, const float* __restrict__ Wo,
    const float* __restrict__ bo, float* __restrict__ out)
{
    const int t   = blockIdx.x;
    const int tid = threadIdx.x;
    __shared__ float zs[EMB];
    zs[tid]       = Z[(size_t)t * EMB + tid];
    zs[tid + 256] = Z[(size_t)t * EMB + tid + 256];
    __syncthreads();

    #pragma unroll
    for (int oo = 0; oo < 2; ++oo) {
        const int o = tid + oo * 256;
        const float4* wr = reinterpret_cast<const float4*>(Wo + (size_t)o * EMB);
        float acc = bo[o];
        #pragma unroll 8
        for (int i = 0; i < EMB / 4; ++i) {
            float4 w4 = wr[i];
            acc += w4.x * zs[4 * i] + w4.y * zs[4 * i + 1] + w4.z * zs[4 * i + 2] + w4.w * zs[4 * i + 3];
        }
        out[(size_t)t * EMB + o] = acc;
    }
}

extern "C" void kernel_launch(void* const* d_in, const int* in_sizes, int n_in,
                              void* d_out, int out_size, void* d_ws, size_t ws_size,
                              hipStream_t stream) {
    const float* v  = (const float*)d_in[0];
    const float* k  = (const float*)d_in[1];
    const float* q  = (const float*)d_in[2];
    const float* Wv = (const float*)d_in[3];
    const float* bv = (const float*)d_in[4];
    const float* Wk = (const float*)d_in[5];
    const float* bk = (const float*)d_in[6];
    const float* Wq = (const float*)d_in[7];
    const float* bq = (const float*)d_in[8];
    const float* E  = (const float*)d_in[9];
    const float* Wo = (const float*)d_in[10];
    const float* bo = (const float*)d_in[11];
    float* out = (float*)d_out;

    ushort* wsu = (ushort*)d_ws;
    const size_t perE = (size_t)NB * NHEADS * SEQLEN * HD;   // 2,097,152
    ushort* Qh = wsu;
    ushort* Kh = wsu + perE;
    ushort* Vh = wsu + 2 * perE;
    ushort* VT = wsu + 3 * perE;
    ushort* Eb = wsu + 4 * perE;
    float*  Zb = (float*)(wsu + 4 * perE + 262144);   // 16B-aligned offset

    dim3 g1(NB * SEQLEN * NHEADS / 4, 3);
    proj_kernel<<<g1, 256, 0, stream>>>(q, k, v, Wq, bq, Wk, bk, Wv, bv, Qh, Kh, Vh);

    dim3 gt(SEQLEN / 64, NHEADS, NB);
    vtrans_kernel<<<gt, 256, 0, stream>>>(Vh, VT);

    econv_kernel<<<SEQLEN * HD / (256 * 4), 256, 0, stream>>>(E, Eb);

    dim3 g2(SEQLEN / 64, NHEADS, NB);
    attn_mfma<<<g2, 256, 0, stream>>>(Qh, Kh, VT, Eb, Zb);

    oproj_kernel<<<NB * SEQLEN, 256, 0, stream>>>(Zb, Wo, bo, out);
}

// Round 4
// 232.330 us; speedup vs baseline: 13.1833x; 2.8877x over previous
//
#include <hip/hip_runtime.h>
#include <hip/hip_bf16.h>

#define SEQLEN 2048
#define NHEADS 8
#define HD 64
#define EMB 512
#define NB 2
#define ST 72   // padded LDS stride in bf16 units (144 B = 9 x 16B -> full bank spread)

typedef __attribute__((ext_vector_type(8))) short bf16x8;
typedef __attribute__((ext_vector_type(4))) float f32x4;

#define SCALE 0.04419417382415922f
#define NEGS  (-4.4194173824159216e18f)   // -1e20 * SCALE (faithful masked score)

__device__ __forceinline__ ushort f2b(float f) {
    __hip_bfloat16 h = __float2bfloat16(f);
    return *reinterpret_cast<ushort*>(&h);
}
__device__ __forceinline__ float b2f(ushort u) {
    unsigned int v = ((unsigned int)u) << 16;
    return __builtin_bit_cast(float, v);
}

// ---------------- Kernel 1: per-head QKV projections (bf16 out) ----------------
__global__ __launch_bounds__(256) void proj_kernel(
    const float* __restrict__ q, const float* __restrict__ k, const float* __restrict__ v,
    const float* __restrict__ Wq, const float* __restrict__ bq,
    const float* __restrict__ Wk, const float* __restrict__ bk,
    const float* __restrict__ Wv, const float* __restrict__ bv,
    ushort* __restrict__ Qh, ushort* __restrict__ Kh, ushort* __restrict__ Vh)
{
    const float* x; const float* W; const float* b; ushort* dst;
    switch (blockIdx.y) {
      case 0:  x = q; W = Wq; b = bq; dst = Qh; break;
      case 1:  x = k; W = Wk; b = bk; dst = Kh; break;
      default: x = v; W = Wv; b = bv; dst = Vh; break;
    }
    __shared__ float Ws[64 * 65];
    __shared__ float Bs[64];
    const int tid = threadIdx.x;
    for (int idx = tid; idx < 64 * 64; idx += 256)
        Ws[(idx >> 6) * 65 + (idx & 63)] = W[idx];
    if (tid < 64) Bs[tid] = b[tid];
    __syncthreads();

    const int r = blockIdx.x * 4 + (tid >> 6);
    const int d = tid & 63;
    const int n   = r / (SEQLEN * NHEADS);
    const int rem = r - n * (SEQLEN * NHEADS);
    const int s   = rem / NHEADS;
    const int h   = rem - s * NHEADS;

    const float* xr = x + ((size_t)(n * SEQLEN + s)) * EMB + h * HD;
    const float* wr = Ws + d * 65;
    float acc = Bs[d];
    #pragma unroll 16
    for (int j = 0; j < 64; ++j)
        acc += wr[j] * xr[j];
    dst[(((size_t)(n * NHEADS + h)) * SEQLEN + s) * HD + d] = f2b(acc);
}

// ---------------- Kernel 1b: V transpose  [n,h,s,d] -> [n,h,d,s] ----------------
__global__ __launch_bounds__(256) void vtrans_kernel(
    const ushort* __restrict__ Vh, ushort* __restrict__ VT)
{
    __shared__ alignas(16) ushort ts[64 * 72];
    const int tid = threadIdx.x;
    const int s0 = blockIdx.x * 64;
    const size_t hb = ((size_t)(blockIdx.z * NHEADS + blockIdx.y)) * SEQLEN * HD;
    const int r = tid >> 2;
    const int cc = (tid & 3) * 16;
    uint4 a = *(const uint4*)(Vh + hb + (size_t)(s0 + r) * HD + cc);
    uint4 b = *(const uint4*)(Vh + hb + (size_t)(s0 + r) * HD + cc + 8);
    *(uint4*)&ts[r * 72 + cc] = a;
    *(uint4*)&ts[r * 72 + cc + 8] = b;
    __syncthreads();
    const int d = tid >> 2;
    const int sc0 = (tid & 3) * 16;
    ushort tmp[16];
    #pragma unroll
    for (int i = 0; i < 16; ++i) tmp[i] = ts[(sc0 + i) * 72 + d];
    *(uint4*)(VT + hb + (size_t)d * SEQLEN + s0 + sc0)     = *(uint4*)&tmp[0];
    *(uint4*)(VT + hb + (size_t)d * SEQLEN + s0 + sc0 + 8) = *(uint4*)&tmp[8];
}

// ---------------- Kernel 1c: f32 -> bf16 bulk convert (E, Wo) ----------------
__global__ __launch_bounds__(256) void econv_kernel(
    const float* __restrict__ E, ushort* __restrict__ Eb)
{
    const int i = (blockIdx.x * 256 + threadIdx.x) * 4;
    float4 f = *(const float4*)(E + i);
    ushort4 u;
    u.x = f2b(f.x); u.y = f2b(f.y); u.z = f2b(f.z); u.w = f2b(f.w);
    *(ushort4*)(Eb + i) = u;
}

// ---------------- Kernel 2: MFMA flash attention with skewed rel-pos ----------------
// grid (S/64, H, N), 256 threads = 4 waves; wave w owns rows qw..qw+15.
// z[q] = (1/l) * sum_{c} e[q,c] V[c]  +  sum_{c<=q} (Q[q]*E[S-1-q+c]) V[c]
__global__ __launch_bounds__(256, 2) void attn_mfma(
    const ushort* __restrict__ Qh, const ushort* __restrict__ Kh,
    const ushort* __restrict__ VT, const ushort* __restrict__ Eb,
    ushort* __restrict__ Z)
{
    const int q0 = blockIdx.x * 64;
    const int h = blockIdx.y, n = blockIdx.z;
    const int tid = threadIdx.x;
    const int w = tid >> 6;
    const int l = tid & 63;
    const int l15 = l & 15, l16 = l >> 4;

    __shared__ alignas(16) ushort Kt[64 * ST];
    __shared__ alignas(16) ushort Vt[64 * ST];      // transposed: Vt[d][c]
    __shared__ alignas(16) ushort Et[128 * ST];
    __shared__ alignas(16) ushort Wt[4][16 * ST];   // per-wave weight tile
    __shared__ float vpart[4][64];
    __shared__ float vsum[64];

    const size_t hb = ((size_t)(n * NHEADS + h)) * SEQLEN * HD;
    const bool lastBlk = (q0 == SEQLEN - 64);
    const int qw = q0 + 16 * w;

    // Q A-fragments (rows qw + l15, k-chunks)
    bf16x8 qa[2];
    {
        const ushort* qp = Qh + hb + (size_t)(qw + l15) * HD + l16 * 8;
        qa[0] = *(const bf16x8*)(qp);
        qa[1] = *(const bf16x8*)(qp + 32);
    }

    f32x4 zp[4], zr[4];
    #pragma unroll
    for (int nb = 0; nb < 4; ++nb) {
        zp[nb] = (f32x4){0.f, 0.f, 0.f, 0.f};
        zr[nb] = (f32x4){0.f, 0.f, 0.f, 0.f};
    }
    float mrow[4], lrow[4];
    #pragma unroll
    for (int r = 0; r < 4; ++r) { mrow[r] = NEGS; lrow[r] = 0.f; }
    float vloc = 0.f;

    for (int t = 0; t < 32; ++t) {
        const int c0 = t * 64;
        const bool hasP = (c0 >= q0);
        const bool hasR = (c0 <= q0);
        const bool diag = (c0 == q0);

        __syncthreads();   // prev tile's PV done before restaging
        {
            const int r8 = tid >> 3;
            const int ch8 = (tid & 7) * 8;
            uint4 v0 = *(const uint4*)(VT + hb + (size_t)r8 * SEQLEN + c0 + ch8);
            uint4 v1 = *(const uint4*)(VT + hb + (size_t)(r8 + 32) * SEQLEN + c0 + ch8);
            uint4 k0, k1;
            if (hasP) {
                k0 = *(const uint4*)(Kh + hb + (size_t)(c0 + r8) * HD + ch8);
                k1 = *(const uint4*)(Kh + hb + (size_t)(c0 + r8 + 32) * HD + ch8);
            }
            uint4 e[4];
            int jmin = 0;
            if (hasR) {
                jmin = SEQLEN - 64 - q0 + c0;
                #pragma unroll
                for (int i = 0; i < 4; ++i) {
                    const int j = jmin + r8 + 32 * i;
                    if (j < SEQLEN) e[i] = *(const uint4*)(Eb + (size_t)j * HD + ch8);
                    else e[i] = make_uint4(0u, 0u, 0u, 0u);
                }
            }
            *(uint4*)&Vt[r8 * ST + ch8] = v0;
            *(uint4*)&Vt[(r8 + 32) * ST + ch8] = v1;
            if (hasP) {
                *(uint4*)&Kt[r8 * ST + ch8] = k0;
                *(uint4*)&Kt[(r8 + 32) * ST + ch8] = k1;
            }
            if (hasR) {
                #pragma unroll
                for (int i = 0; i < 4; ++i)
                    *(uint4*)&Et[(r8 + 32 * i) * ST + ch8] = e[i];
            }
        }
        __syncthreads();

        if (lastBlk) {   // accumulate column-sum of V (for uniform row S-1)
            const uint4 a = *(const uint4*)&Vt[l * ST + 16 * w];
            const uint4 b = *(const uint4*)&Vt[l * ST + 16 * w + 8];
            const ushort* pa = (const ushort*)&a;
            const ushort* pb = (const ushort*)&b;
            #pragma unroll
            for (int i = 0; i < 8; ++i) vloc += b2f(pa[i]) + b2f(pb[i]);
        }

        // ---------- P (softmax) part ----------
        if (hasP) {
            f32x4 sc[4];
            #pragma unroll
            for (int nb = 0; nb < 4; ++nb) sc[nb] = (f32x4){0.f, 0.f, 0.f, 0.f};
            #pragma unroll
            for (int ks = 0; ks < 2; ++ks) {
                const int ko = ks * 32 + l16 * 8;
                #pragma unroll
                for (int nb = 0; nb < 4; ++nb) {
                    bf16x8 kb = *(const bf16x8*)&Kt[(nb * 16 + l15) * ST + ko];
                    sc[nb] = __builtin_amdgcn_mfma_f32_16x16x32_bf16(qa[ks], kb, sc[nb], 0, 0, 0);
                }
            }
            float sv[4][4], mt[4], frs[4];
            #pragma unroll
            for (int r = 0; r < 4; ++r) mt[r] = NEGS;
            #pragma unroll
            for (int nb = 0; nb < 4; ++nb)
                #pragma unroll
                for (int r = 0; r < 4; ++r) {
                    float s = sc[nb][r] * SCALE;
                    if (diag && (nb * 16 + l15 <= 16 * w + l16 * 4 + r)) s = NEGS;
                    sv[nb][r] = s;
                    mt[r] = fmaxf(mt[r], s);
                }
            #pragma unroll
            for (int r = 0; r < 4; ++r) {
                #pragma unroll
                for (int off = 1; off < 16; off <<= 1)
                    mt[r] = fmaxf(mt[r], __shfl_xor(mt[r], off, 64));
                const float mn = fmaxf(mrow[r], mt[r]);
                frs[r] = __expf(mrow[r] - mn);
                mrow[r] = mn;
                lrow[r] *= frs[r];
            }
            float se[4] = {0.f, 0.f, 0.f, 0.f};
            #pragma unroll
            for (int nb = 0; nb < 4; ++nb)
                #pragma unroll
                for (int r = 0; r < 4; ++r) {
                    const float e = __expf(sv[nb][r] - mrow[r]);
                    se[r] += e;
                    Wt[w][(l16 * 4 + r) * ST + nb * 16 + l15] = f2b(e);
                }
            #pragma unroll
            for (int r = 0; r < 4; ++r) {
                #pragma unroll
                for (int off = 1; off < 16; off <<= 1)
                    se[r] += __shfl_xor(se[r], off, 64);
                lrow[r] += se[r];
            }
            #pragma unroll
            for (int nb = 0; nb < 4; ++nb)
                #pragma unroll
                for (int r = 0; r < 4; ++r) zp[nb][r] *= frs[r];
            // PV into zp (reads own wave's Wt; in-wave ds ordering by compiler)
            #pragma unroll
            for (int ks = 0; ks < 2; ++ks) {
                const int ko = ks * 32 + l16 * 8;
                bf16x8 wa = *(const bf16x8*)&Wt[w][l15 * ST + ko];
                #pragma unroll
                for (int nb = 0; nb < 4; ++nb) {
                    bf16x8 vb = *(const bf16x8*)&Vt[(nb * 16 + l15) * ST + ko];
                    zp[nb] = __builtin_amdgcn_mfma_f32_16x16x32_bf16(wa, vb, zp[nb], 0, 0, 0);
                }
            }
        }

        // ---------- rel (Srel) part ----------
        if (hasR) {
            const int jbase = 48 - 16 * w;   // wave's window into Et
            f32x4 qe[5];
            #pragma unroll
            for (int jb = 0; jb < 5; ++jb) qe[jb] = (f32x4){0.f, 0.f, 0.f, 0.f};
            #pragma unroll
            for (int ks = 0; ks < 2; ++ks) {
                const int ko = ks * 32 + l16 * 8;
                #pragma unroll
                for (int jb = 0; jb < 5; ++jb) {
                    bf16x8 eb = *(const bf16x8*)&Et[(jbase + jb * 16 + l15) * ST + ko];
                    qe[jb] = __builtin_amdgcn_mfma_f32_16x16x32_bf16(qa[ks], eb, qe[jb], 0, 0, 0);
                }
            }
            // scatter skewed: (q, j) -> (q, cloc = jl + rowloc - 15); write srel if c<=q else 0
            #pragma unroll
            for (int jb = 0; jb < 5; ++jb)
                #pragma unroll
                for (int r = 0; r < 4; ++r) {
                    const int rowloc = l16 * 4 + r;
                    const int cloc = jb * 16 + l15 + rowloc - 15;
                    if (cloc >= 0 && cloc < 64) {
                        const bool msk = (c0 + cloc <= qw + rowloc);
                        Wt[w][rowloc * ST + cloc] = f2b(msk ? qe[jb][r] : 0.f);
                    }
                }
            // PV into zr
            #pragma unroll
            for (int ks = 0; ks < 2; ++ks) {
                const int ko = ks * 32 + l16 * 8;
                bf16x8 wa = *(const bf16x8*)&Wt[w][l15 * ST + ko];
                #pragma unroll
                for (int nb = 0; nb < 4; ++nb) {
                    bf16x8 vb = *(const bf16x8*)&Vt[(nb * 16 + l15) * ST + ko];
                    zr[nb] = __builtin_amdgcn_mfma_f32_16x16x32_bf16(wa, vb, zr[nb], 0, 0, 0);
                }
            }
        }
    }

    // ---------- vsum finalize (uniform row S-1) ----------
    if (lastBlk) vpart[w][l] = vloc;
    __syncthreads();
    if (lastBlk && tid < 64)
        vsum[tid] = vpart[0][tid] + vpart[1][tid] + vpart[2][tid] + vpart[3][tid];
    __syncthreads();

    // ---------- epilogue (bf16 out) ----------
    float invl[4];
    #pragma unroll
    for (int r = 0; r < 4; ++r) invl[r] = 1.f / lrow[r];
    #pragma unroll
    for (int nb = 0; nb < 4; ++nb)
        #pragma unroll
        for (int r = 0; r < 4; ++r) {
            const int q = qw + l16 * 4 + r;
            const int d = nb * 16 + l15;
            float z = zp[nb][r] * invl[r] + zr[nb][r];
            if (lastBlk && q == SEQLEN - 1)
                z = vsum[d] * (1.f / (float)SEQLEN) + zr[nb][r];
            Z[((size_t)(n * SEQLEN + q)) * EMB + h * HD + d] = f2b(z);
        }
}

// ---------------- Kernel 3: output projection via MFMA ----------------
// out[t,o] = bo[o] + sum_k Zb[t,k] * Wob[o,k];  M=4096, N=512, K=512
// grid (M/64, N/64), 256 thr = 4 waves in 2x2; each wave 32x32 (2x2 frags).
__global__ __launch_bounds__(256, 4) void oproj_mfma(
    const ushort* __restrict__ Zb, const ushort* __restrict__ Wob,
    const float* __restrict__ bo, float* __restrict__ out)
{
    __shared__ alignas(16) ushort At[64 * ST];
    __shared__ alignas(16) ushort Bt[64 * ST];
    const int tid = threadIdx.x;
    const int w = tid >> 6, l = tid & 63;
    const int l15 = l & 15, l16 = l >> 4;
    const int m0 = blockIdx.x * 64;
    const int n0 = blockIdx.y * 64;
    const int wm = (w >> 1) * 32, wn = (w & 1) * 32;
    const int r8 = tid >> 3, ch8 = (tid & 7) * 8;

    f32x4 acc[2][2];
    #pragma unroll
    for (int i = 0; i < 2; ++i)
        #pragma unroll
        for (int j = 0; j < 2; ++j) acc[i][j] = (f32x4){0.f, 0.f, 0.f, 0.f};

    for (int kt = 0; kt < 8; ++kt) {
        const int k0 = kt * 64;
        __syncthreads();
        {
            uint4 a0 = *(const uint4*)(Zb  + (size_t)(m0 + r8) * EMB + k0 + ch8);
            uint4 a1 = *(const uint4*)(Zb  + (size_t)(m0 + r8 + 32) * EMB + k0 + ch8);
            uint4 b0 = *(const uint4*)(Wob + (size_t)(n0 + r8) * EMB + k0 + ch8);
            uint4 b1 = *(const uint4*)(Wob + (size_t)(n0 + r8 + 32) * EMB + k0 + ch8);
            *(uint4*)&At[r8 * ST + ch8] = a0;
            *(uint4*)&At[(r8 + 32) * ST + ch8] = a1;
            *(uint4*)&Bt[r8 * ST + ch8] = b0;
            *(uint4*)&Bt[(r8 + 32) * ST + ch8] = b1;
        }
        __syncthreads();
        #pragma unroll
        for (int ks = 0; ks < 2; ++ks) {
            const int ko = ks * 32 + l16 * 8;
            bf16x8 af[2], bf[2];
            #pragma unroll
            for (int i = 0; i < 2; ++i) {
                af[i] = *(const bf16x8*)&At[(wm + i * 16 + l15) * ST + ko];
                bf[i] = *(const bf16x8*)&Bt[(wn + i * 16 + l15) * ST + ko];
            }
            #pragma unroll
            for (int i = 0; i < 2; ++i)
                #pragma unroll
                for (int j = 0; j < 2; ++j)
                    acc[i][j] = __builtin_amdgcn_mfma_f32_16x16x32_bf16(af[i], bf[j], acc[i][j], 0, 0, 0);
        }
    }

    #pragma unroll
    for (int i = 0; i < 2; ++i)
        #pragma unroll
        for (int j = 0; j < 2; ++j) {
            const int o = n0 + wn + j * 16 + l15;
            const float bb = bo[o];
            #pragma unroll
            for (int r = 0; r < 4; ++r) {
                const int t = m0 + wm + i * 16 + l16 * 4 + r;
                out[(size_t)t * EMB + o] = acc[i][j][r] + bb;
            }
        }
}

extern "C" void kernel_launch(void* const* d_in, const int* in_sizes, int n_in,
                              void* d_out, int out_size, void* d_ws, size_t ws_size,
                              hipStream_t stream) {
    const float* v  = (const float*)d_in[0];
    const float* k  = (const float*)d_in[1];
    const float* q  = (const float*)d_in[2];
    const float* Wv = (const float*)d_in[3];
    const float* bv = (const float*)d_in[4];
    const float* Wk = (const float*)d_in[5];
    const float* bk = (const float*)d_in[6];
    const float* Wq = (const float*)d_in[7];
    const float* bq = (const float*)d_in[8];
    const float* E  = (const float*)d_in[9];
    const float* Wo = (const float*)d_in[10];
    const float* bo = (const float*)d_in[11];
    float* out = (float*)d_out;

    ushort* wsu = (ushort*)d_ws;
    const size_t perE = (size_t)NB * NHEADS * SEQLEN * HD;   // 2,097,152
    ushort* Qh  = wsu;
    ushort* Kh  = wsu + perE;
    ushort* Vh  = wsu + 2 * perE;
    ushort* VT  = wsu + 3 * perE;
    ushort* Eb  = wsu + 4 * perE;                  // 131072
    ushort* Wob = wsu + 4 * perE + 131072;         // 262144
    ushort* Zb  = wsu + 4 * perE + 131072 + 262144;// 2,097,152 (bf16 [4096,512])

    dim3 g1(NB * SEQLEN * NHEADS / 4, 3);
    proj_kernel<<<g1, 256, 0, stream>>>(q, k, v, Wq, bq, Wk, bk, Wv, bv, Qh, Kh, Vh);

    dim3 gt(SEQLEN / 64, NHEADS, NB);
    vtrans_kernel<<<gt, 256, 0, stream>>>(Vh, VT);

    econv_kernel<<<SEQLEN * HD / (256 * 4), 256, 0, stream>>>(E, Eb);
    econv_kernel<<<EMB * EMB / (256 * 4), 256, 0, stream>>>(Wo, Wob);

    dim3 g2(SEQLEN / 64, NHEADS, NB);
    attn_mfma<<<g2, 256, 0, stream>>>(Qh, Kh, VT, Eb, Zb);

    dim3 g3(NB * SEQLEN / 64, EMB / 64);
    oproj_mfma<<<g3, 256, 0, stream>>>(Zb, Wob, bo, out);
}

// Round 5
// 174.305 us; speedup vs baseline: 17.5720x; 1.3329x over previous
//
#include <hip/hip_runtime.h>
#include <hip/hip_bf16.h>

#define SEQLEN 2048
#define NHEADS 8
#define HD 64
#define EMB 512
#define NB 2
#define ST 72   // padded LDS stride in bf16 units (144 B = 9 x 16B -> full bank spread)

typedef __attribute__((ext_vector_type(8))) short bf16x8;
typedef __attribute__((ext_vector_type(4))) float f32x4;

#define SCALE 0.04419417382415922f
#define NEGS  (-4.4194173824159216e18f)   // -1e20 * SCALE (faithful masked score)

__device__ __forceinline__ ushort f2b(float f) {
    __hip_bfloat16 h = __float2bfloat16(f);
    return *reinterpret_cast<ushort*>(&h);
}
__device__ __forceinline__ float b2f(ushort u) {
    unsigned int v = ((unsigned int)u) << 16;
    return __builtin_bit_cast(float, v);
}
__device__ __forceinline__ uint4 pack8(float4 a, float4 b) {
    union { ushort u[8]; uint4 v; } r;
    r.u[0] = f2b(a.x); r.u[1] = f2b(a.y); r.u[2] = f2b(a.z); r.u[3] = f2b(a.w);
    r.u[4] = f2b(b.x); r.u[5] = f2b(b.y); r.u[6] = f2b(b.z); r.u[7] = f2b(b.w);
    return r.v;
}

// ---------------- Kernel 1: per-head QKV projections via MFMA ----------------
// grid (NB*S/64, H, 3). out[s,o] = b[o] + sum_j x[s, h*64+j] * W[o,j]
// mat 0 -> Qh [n,h,s,d], mat 1 -> Kh [n,h,s,d], mat 2 -> VT [n,h,d,s] (transposed)
__global__ __launch_bounds__(256, 4) void proj_mfma(
    const float* __restrict__ q, const float* __restrict__ k, const float* __restrict__ v,
    const float* __restrict__ Wq, const float* __restrict__ bq,
    const float* __restrict__ Wk, const float* __restrict__ bk,
    const float* __restrict__ Wv, const float* __restrict__ bv,
    ushort* __restrict__ Qh, ushort* __restrict__ Kh, ushort* __restrict__ VT)
{
    const int mat = blockIdx.z;
    const float* x; const float* W; const float* b;
    switch (mat) {
      case 0:  x = q; W = Wq; b = bq; break;
      case 1:  x = k; W = Wk; b = bk; break;
      default: x = v; W = Wv; b = bv; break;
    }
    __shared__ alignas(16) ushort At[64 * ST];
    __shared__ alignas(16) ushort Bt[64 * ST];
    __shared__ alignas(16) ushort Ct[64 * ST];

    const int tid = threadIdx.x;
    const int w = tid >> 6, l = tid & 63;
    const int l15 = l & 15, l16 = l >> 4;
    const int h  = blockIdx.y;
    const int m0 = blockIdx.x * 64;          // row in [0, NB*SEQLEN)
    const int n  = m0 / SEQLEN;
    const int s0 = m0 - n * SEQLEN;
    const int wm = (w >> 1) * 32, wn = (w & 1) * 32;
    const int r8 = tid >> 3, ch8 = (tid & 7) * 8;

    {   // stage A (x tile) and B (W) as bf16
        const float* xr0 = x + (size_t)(m0 + r8) * EMB + h * HD + ch8;
        const float* xr1 = x + (size_t)(m0 + r8 + 32) * EMB + h * HD + ch8;
        float4 a0 = *(const float4*)xr0, a1 = *(const float4*)(xr0 + 4);
        float4 a2 = *(const float4*)xr1, a3 = *(const float4*)(xr1 + 4);
        const float* wr0 = W + r8 * HD + ch8;
        const float* wr1 = W + (r8 + 32) * HD + ch8;
        float4 b0 = *(const float4*)wr0, b1 = *(const float4*)(wr0 + 4);
        float4 b2 = *(const float4*)wr1, b3 = *(const float4*)(wr1 + 4);
        *(uint4*)&At[r8 * ST + ch8]        = pack8(a0, a1);
        *(uint4*)&At[(r8 + 32) * ST + ch8] = pack8(a2, a3);
        *(uint4*)&Bt[r8 * ST + ch8]        = pack8(b0, b1);
        *(uint4*)&Bt[(r8 + 32) * ST + ch8] = pack8(b2, b3);
    }
    __syncthreads();

    f32x4 acc[2][2];
    #pragma unroll
    for (int i = 0; i < 2; ++i)
        #pragma unroll
        for (int j = 0; j < 2; ++j) acc[i][j] = (f32x4){0.f, 0.f, 0.f, 0.f};

    #pragma unroll
    for (int ks = 0; ks < 2; ++ks) {
        const int ko = ks * 32 + l16 * 8;
        bf16x8 af[2], bf[2];
        #pragma unroll
        for (int i = 0; i < 2; ++i) {
            af[i] = *(const bf16x8*)&At[(wm + i * 16 + l15) * ST + ko];
            bf[i] = *(const bf16x8*)&Bt[(wn + i * 16 + l15) * ST + ko];
        }
        #pragma unroll
        for (int i = 0; i < 2; ++i)
            #pragma unroll
            for (int j = 0; j < 2; ++j)
                acc[i][j] = __builtin_amdgcn_mfma_f32_16x16x32_bf16(af[i], bf[j], acc[i][j], 0, 0, 0);
    }

    // bias + store C tile to LDS (transposed for V)
    float bb[2];
    #pragma unroll
    for (int j = 0; j < 2; ++j) bb[j] = b[wn + j * 16 + l15];
    #pragma unroll
    for (int i = 0; i < 2; ++i)
        #pragma unroll
        for (int j = 0; j < 2; ++j)
            #pragma unroll
            for (int r = 0; r < 4; ++r) {
                const int srow = wm + i * 16 + l16 * 4 + r;
                const int dcol = wn + j * 16 + l15;
                const ushort val = f2b(acc[i][j][r] + bb[j]);
                if (mat < 2) Ct[srow * ST + dcol] = val;
                else         Ct[dcol * ST + srow] = val;
            }
    __syncthreads();

    const size_t hb = ((size_t)(n * NHEADS + h)) * SEQLEN * HD;
    if (mat < 2) {
        ushort* dst = (mat == 0 ? Qh : Kh);
        *(uint4*)(dst + hb + (size_t)(s0 + r8) * HD + ch8)      = *(uint4*)&Ct[r8 * ST + ch8];
        *(uint4*)(dst + hb + (size_t)(s0 + r8 + 32) * HD + ch8) = *(uint4*)&Ct[(r8 + 32) * ST + ch8];
    } else {
        // Ct rows are d; write VT[d][s0..s0+63] coalesced
        *(uint4*)(VT + hb + (size_t)r8 * SEQLEN + s0 + ch8)        = *(uint4*)&Ct[r8 * ST + ch8];
        *(uint4*)(VT + hb + (size_t)(r8 + 32) * SEQLEN + s0 + ch8) = *(uint4*)&Ct[(r8 + 32) * ST + ch8];
    }
}

// ---------------- Kernel 1c: f32 -> bf16 bulk convert (E, Wo) ----------------
__global__ __launch_bounds__(256) void econv_kernel(
    const float* __restrict__ E, ushort* __restrict__ Eb)
{
    const int i = (blockIdx.x * 256 + threadIdx.x) * 4;
    float4 f = *(const float4*)(E + i);
    ushort4 u;
    u.x = f2b(f.x); u.y = f2b(f.y); u.z = f2b(f.z); u.w = f2b(f.w);
    *(ushort4*)(Eb + i) = u;
}

// ---------------- Kernel 2: MFMA flash attention with skewed rel-pos ----------------
// grid (S/64, H, N), 256 threads = 4 waves; wave w owns rows qw..qw+15.
// z[q] = (1/l) * sum_{c} e[q,c] V[c]  +  sum_{c<=q} (Q[q]*E[S-1-q+c]) V[c]
__global__ __launch_bounds__(256, 2) void attn_mfma(
    const ushort* __restrict__ Qh, const ushort* __restrict__ Kh,
    const ushort* __restrict__ VT, const ushort* __restrict__ Eb,
    ushort* __restrict__ Z)
{
    const int q0 = blockIdx.x * 64;
    const int h = blockIdx.y, n = blockIdx.z;
    const int tid = threadIdx.x;
    const int w = tid >> 6;
    const int l = tid & 63;
    const int l15 = l & 15, l16 = l >> 4;

    __shared__ alignas(16) ushort Kt[64 * ST];
    __shared__ alignas(16) ushort Vt[64 * ST];      // transposed: Vt[d][c]
    __shared__ alignas(16) ushort Et[128 * ST];
    __shared__ alignas(16) ushort Wt[4][16 * ST];   // per-wave weight tile
    __shared__ float vpart[4][64];
    __shared__ float vsum[64];

    const size_t hb = ((size_t)(n * NHEADS + h)) * SEQLEN * HD;
    const bool lastBlk = (q0 == SEQLEN - 64);
    const int qw = q0 + 16 * w;

    // Q A-fragments (rows qw + l15, k-chunks)
    bf16x8 qa[2];
    {
        const ushort* qp = Qh + hb + (size_t)(qw + l15) * HD + l16 * 8;
        qa[0] = *(const bf16x8*)(qp);
        qa[1] = *(const bf16x8*)(qp + 32);
    }

    f32x4 zp[4], zr[4];
    #pragma unroll
    for (int nb = 0; nb < 4; ++nb) {
        zp[nb] = (f32x4){0.f, 0.f, 0.f, 0.f};
        zr[nb] = (f32x4){0.f, 0.f, 0.f, 0.f};
    }
    float mrow[4], lrow[4];
    #pragma unroll
    for (int r = 0; r < 4; ++r) { mrow[r] = NEGS; lrow[r] = 0.f; }
    float vloc = 0.f;

    for (int t = 0; t < 32; ++t) {
        const int c0 = t * 64;
        const bool hasP = (c0 >= q0);
        const bool hasR = (c0 <= q0);
        const bool diag = (c0 == q0);

        __syncthreads();   // prev tile's PV done before restaging
        {
            const int r8 = tid >> 3;
            const int ch8 = (tid & 7) * 8;
            uint4 v0 = *(const uint4*)(VT + hb + (size_t)r8 * SEQLEN + c0 + ch8);
            uint4 v1 = *(const uint4*)(VT + hb + (size_t)(r8 + 32) * SEQLEN + c0 + ch8);
            uint4 k0, k1;
            if (hasP) {
                k0 = *(const uint4*)(Kh + hb + (size_t)(c0 + r8) * HD + ch8);
                k1 = *(const uint4*)(Kh + hb + (size_t)(c0 + r8 + 32) * HD + ch8);
            }
            uint4 e[4];
            int jmin = 0;
            if (hasR) {
                jmin = SEQLEN - 64 - q0 + c0;
                #pragma unroll
                for (int i = 0; i < 4; ++i) {
                    const int j = jmin + r8 + 32 * i;
                    if (j < SEQLEN) e[i] = *(const uint4*)(Eb + (size_t)j * HD + ch8);
                    else e[i] = make_uint4(0u, 0u, 0u, 0u);
                }
            }
            *(uint4*)&Vt[r8 * ST + ch8] = v0;
            *(uint4*)&Vt[(r8 + 32) * ST + ch8] = v1;
            if (hasP) {
                *(uint4*)&Kt[r8 * ST + ch8] = k0;
                *(uint4*)&Kt[(r8 + 32) * ST + ch8] = k1;
            }
            if (hasR) {
                #pragma unroll
                for (int i = 0; i < 4; ++i)
                    *(uint4*)&Et[(r8 + 32 * i) * ST + ch8] = e[i];
            }
        }
        __syncthreads();

        if (lastBlk) {   // accumulate column-sum of V (for uniform row S-1)
            const uint4 a = *(const uint4*)&Vt[l * ST + 16 * w];
            const uint4 b = *(const uint4*)&Vt[l * ST + 16 * w + 8];
            const ushort* pa = (const ushort*)&a;
            const ushort* pb = (const ushort*)&b;
            #pragma unroll
            for (int i = 0; i < 8; ++i) vloc += b2f(pa[i]) + b2f(pb[i]);
        }

        // ---------- P (softmax) part ----------
        if (hasP) {
            f32x4 sc[4];
            #pragma unroll
            for (int nb = 0; nb < 4; ++nb) sc[nb] = (f32x4){0.f, 0.f, 0.f, 0.f};
            #pragma unroll
            for (int ks = 0; ks < 2; ++ks) {
                const int ko = ks * 32 + l16 * 8;
                #pragma unroll
                for (int nb = 0; nb < 4; ++nb) {
                    bf16x8 kb = *(const bf16x8*)&Kt[(nb * 16 + l15) * ST + ko];
                    sc[nb] = __builtin_amdgcn_mfma_f32_16x16x32_bf16(qa[ks], kb, sc[nb], 0, 0, 0);
                }
            }
            float sv[4][4], mt[4], frs[4];
            #pragma unroll
            for (int r = 0; r < 4; ++r) mt[r] = NEGS;
            #pragma unroll
            for (int nb = 0; nb < 4; ++nb)
                #pragma unroll
                for (int r = 0; r < 4; ++r) {
                    float s = sc[nb][r] * SCALE;
                    if (diag && (nb * 16 + l15 <= 16 * w + l16 * 4 + r)) s = NEGS;
                    sv[nb][r] = s;
                    mt[r] = fmaxf(mt[r], s);
                }
            #pragma unroll
            for (int r = 0; r < 4; ++r) {
                #pragma unroll
                for (int off = 1; off < 16; off <<= 1)
                    mt[r] = fmaxf(mt[r], __shfl_xor(mt[r], off, 64));
                const float mn = fmaxf(mrow[r], mt[r]);
                frs[r] = __expf(mrow[r] - mn);
                mrow[r] = mn;
                lrow[r] *= frs[r];
            }
            float se[4] = {0.f, 0.f, 0.f, 0.f};
            #pragma unroll
            for (int nb = 0; nb < 4; ++nb)
                #pragma unroll
                for (int r = 0; r < 4; ++r) {
                    const float e = __expf(sv[nb][r] - mrow[r]);
                    se[r] += e;
                    Wt[w][(l16 * 4 + r) * ST + nb * 16 + l15] = f2b(e);
                }
            #pragma unroll
            for (int r = 0; r < 4; ++r) {
                #pragma unroll
                for (int off = 1; off < 16; off <<= 1)
                    se[r] += __shfl_xor(se[r], off, 64);
                lrow[r] += se[r];
            }
            #pragma unroll
            for (int nb = 0; nb < 4; ++nb)
                #pragma unroll
                for (int r = 0; r < 4; ++r) zp[nb][r] *= frs[r];
            // PV into zp (reads own wave's Wt; in-wave ds ordering by compiler)
            #pragma unroll
            for (int ks = 0; ks < 2; ++ks) {
                const int ko = ks * 32 + l16 * 8;
                bf16x8 wa = *(const bf16x8*)&Wt[w][l15 * ST + ko];
                #pragma unroll
                for (int nb = 0; nb < 4; ++nb) {
                    bf16x8 vb = *(const bf16x8*)&Vt[(nb * 16 + l15) * ST + ko];
                    zp[nb] = __builtin_amdgcn_mfma_f32_16x16x32_bf16(wa, vb, zp[nb], 0, 0, 0);
                }
            }
        }

        // ---------- rel (Srel) part ----------
        if (hasR) {
            const int jbase = 48 - 16 * w;   // wave's window into Et
            f32x4 qe[5];
            #pragma unroll
            for (int jb = 0; jb < 5; ++jb) qe[jb] = (f32x4){0.f, 0.f, 0.f, 0.f};
            #pragma unroll
            for (int ks = 0; ks < 2; ++ks) {
                const int ko = ks * 32 + l16 * 8;
                #pragma unroll
                for (int jb = 0; jb < 5; ++jb) {
                    bf16x8 eb = *(const bf16x8*)&Et[(jbase + jb * 16 + l15) * ST + ko];
                    qe[jb] = __builtin_amdgcn_mfma_f32_16x16x32_bf16(qa[ks], eb, qe[jb], 0, 0, 0);
                }
            }
            // scatter skewed: (q, j) -> (q, cloc = jl + rowloc - 15); write srel if c<=q else 0
            #pragma unroll
            for (int jb = 0; jb < 5; ++jb)
                #pragma unroll
                for (int r = 0; r < 4; ++r) {
                    const int rowloc = l16 * 4 + r;
                    const int cloc = jb * 16 + l15 + rowloc - 15;
                    if (cloc >= 0 && cloc < 64) {
                        const bool msk = (c0 + cloc <= qw + rowloc);
                        Wt[w][rowloc * ST + cloc] = f2b(msk ? qe[jb][r] : 0.f);
                    }
                }
            // PV into zr
            #pragma unroll
            for (int ks = 0; ks < 2; ++ks) {
                const int ko = ks * 32 + l16 * 8;
                bf16x8 wa = *(const bf16x8*)&Wt[w][l15 * ST + ko];
                #pragma unroll
                for (int nb = 0; nb < 4; ++nb) {
                    bf16x8 vb = *(const bf16x8*)&Vt[(nb * 16 + l15) * ST + ko];
                    zr[nb] = __builtin_amdgcn_mfma_f32_16x16x32_bf16(wa, vb, zr[nb], 0, 0, 0);
                }
            }
        }
    }

    // ---------- vsum finalize (uniform row S-1) ----------
    if (lastBlk) vpart[w][l] = vloc;
    __syncthreads();
    if (lastBlk && tid < 64)
        vsum[tid] = vpart[0][tid] + vpart[1][tid] + vpart[2][tid] + vpart[3][tid];
    __syncthreads();

    // ---------- epilogue (bf16 out) ----------
    float invl[4];
    #pragma unroll
    for (int r = 0; r < 4; ++r) invl[r] = 1.f / lrow[r];
    #pragma unroll
    for (int nb = 0; nb < 4; ++nb)
        #pragma unroll
        for (int r = 0; r < 4; ++r) {
            const int q = qw + l16 * 4 + r;
            const int d = nb * 16 + l15;
            float z = zp[nb][r] * invl[r] + zr[nb][r];
            if (lastBlk && q == SEQLEN - 1)
                z = vsum[d] * (1.f / (float)SEQLEN) + zr[nb][r];
            Z[((size_t)(n * SEQLEN + q)) * EMB + h * HD + d] = f2b(z);
        }
}

// ---------------- Kernel 3: output projection via MFMA ----------------
// out[t,o] = bo[o] + sum_k Zb[t,k] * Wob[o,k];  M=4096, N=512, K=512
// grid (M/64, N/64), 256 thr = 4 waves in 2x2; each wave 32x32 (2x2 frags).
__global__ __launch_bounds__(256, 4) void oproj_mfma(
    const ushort* __restrict__ Zb, const ushort* __restrict__ Wob,
    const float* __restrict__ bo, float* __restrict__ out)
{
    __shared__ alignas(16) ushort At[64 * ST];
    __shared__ alignas(16) ushort Bt[64 * ST];
    const int tid = threadIdx.x;
    const int w = tid >> 6, l = tid & 63;
    const int l15 = l & 15, l16 = l >> 4;
    const int m0 = blockIdx.x * 64;
    const int n0 = blockIdx.y * 64;
    const int wm = (w >> 1) * 32, wn = (w & 1) * 32;
    const int r8 = tid >> 3, ch8 = (tid & 7) * 8;

    f32x4 acc[2][2];
    #pragma unroll
    for (int i = 0; i < 2; ++i)
        #pragma unroll
        for (int j = 0; j < 2; ++j) acc[i][j] = (f32x4){0.f, 0.f, 0.f, 0.f};

    for (int kt = 0; kt < 8; ++kt) {
        const int k0 = kt * 64;
        __syncthreads();
        {
            uint4 a0 = *(const uint4*)(Zb  + (size_t)(m0 + r8) * EMB + k0 + ch8);
            uint4 a1 = *(const uint4*)(Zb  + (size_t)(m0 + r8 + 32) * EMB + k0 + ch8);
            uint4 b0 = *(const uint4*)(Wob + (size_t)(n0 + r8) * EMB + k0 + ch8);
            uint4 b1 = *(const uint4*)(Wob + (size_t)(n0 + r8 + 32) * EMB + k0 + ch8);
            *(uint4*)&At[r8 * ST + ch8] = a0;
            *(uint4*)&At[(r8 + 32) * ST + ch8] = a1;
            *(uint4*)&Bt[r8 * ST + ch8] = b0;
            *(uint4*)&Bt[(r8 + 32) * ST + ch8] = b1;
        }
        __syncthreads();
        #pragma unroll
        for (int ks = 0; ks < 2; ++ks) {
            const int ko = ks * 32 + l16 * 8;
            bf16x8 af[2], bf[2];
            #pragma unroll
            for (int i = 0; i < 2; ++i) {
                af[i] = *(const bf16x8*)&At[(wm + i * 16 + l15) * ST + ko];
                bf[i] = *(const bf16x8*)&Bt[(wn + i * 16 + l15) * ST + ko];
            }
            #pragma unroll
            for (int i = 0; i < 2; ++i)
                #pragma unroll
                for (int j = 0; j < 2; ++j)
                    acc[i][j] = __builtin_amdgcn_mfma_f32_16x16x32_bf16(af[i], bf[j], acc[i][j], 0, 0, 0);
        }
    }

    #pragma unroll
    for (int i = 0; i < 2; ++i)
        #pragma unroll
        for (int j = 0; j < 2; ++j) {
            const int o = n0 + wn + j * 16 + l15;
            const float bb = bo[o];
            #pragma unroll
            for (int r = 0; r < 4; ++r) {
                const int t = m0 + wm + i * 16 + l16 * 4 + r;
                out[(size_t)t * EMB + o] = acc[i][j][r] + bb;
            }
        }
}

extern "C" void kernel_launch(void* const* d_in, const int* in_sizes, int n_in,
                              void* d_out, int out_size, void* d_ws, size_t ws_size,
                              hipStream_t stream) {
    const float* v  = (const float*)d_in[0];
    const float* k  = (const float*)d_in[1];
    const float* q  = (const float*)d_in[2];
    const float* Wv = (const float*)d_in[3];
    const float* bv = (const float*)d_in[4];
    const float* Wk = (const float*)d_in[5];
    const float* bk = (const float*)d_in[6];
    const float* Wq = (const float*)d_in[7];
    const float* bq = (const float*)d_in[8];
    const float* E  = (const float*)d_in[9];
    const float* Wo = (const float*)d_in[10];
    const float* bo = (const float*)d_in[11];
    float* out = (float*)d_out;

    ushort* wsu = (ushort*)d_ws;
    const size_t perE = (size_t)NB * NHEADS * SEQLEN * HD;     // 2,097,152
    ushort* Qh  = wsu;
    ushort* Kh  = wsu + perE;
    ushort* VT  = wsu + 2 * perE;
    ushort* Eb  = wsu + 3 * perE;                              // 131072
    ushort* Wob = wsu + 3 * perE + 131072;                     // 262144
    ushort* Zb  = wsu + 3 * perE + 131072 + 262144;            // 2,097,152

    dim3 gp(NB * SEQLEN / 64, NHEADS, 3);
    proj_mfma<<<gp, 256, 0, stream>>>(q, k, v, Wq, bq, Wk, bk, Wv, bv, Qh, Kh, VT);

    econv_kernel<<<SEQLEN * HD / (256 * 4), 256, 0, stream>>>(E, Eb);
    econv_kernel<<<EMB * EMB / (256 * 4), 256, 0, stream>>>(Wo, Wob);

    dim3 g2(SEQLEN / 64, NHEADS, NB);
    attn_mfma<<<g2, 256, 0, stream>>>(Qh, Kh, VT, Eb, Zb);

    dim3 g3(NB * SEQLEN / 64, EMB / 64);
    oproj_mfma<<<g3, 256, 0, stream>>>(Zb, Wob, bo, out);
}